// Round 5
// baseline (213.304 us; speedup 1.0000x reference)
//
#include <hip/hip_runtime.h>

#define DIM 160
#define SLICE (DIM * DIM)
#define TH 16
#define TW 16
#define CD 40            // output slices per chunk; 4 chunks per batch
#define WSTR 20
#define WPL (24 * WSTR)  // 480 floats per W plane
#define USTR 20
#define UPL (16 * USTR)  // 320 floats per U plane

// Fused LNCC, separable order w -> h -> d. Products never touch LDS.
// Per input slice (48 per chunk), 2 barriers:
//   region R: [A] 96 threads (t>=160): per halo row, 12 x + 12 y values from
//             GLOBAL (3+3 b128, double-buffered in regs across the slice),
//             5 products in registers, 9-tap w-slide -> W[5][24][16] (b128).
//             [C of previous slice runs here too — disjoint arrays.]
//   bar1      W ready
//   [B] 80 threads: 9-tap h-sum W->U, b128 column slide.
//   bar2      U ready
//   [C] 256 threads: one output column each; 9-deep register d-ring
//             (compile-time phase via 9-unrolled loop), ncc emit.
__global__ __launch_bounds__(256, 3)
void lncc_kernel(const float* __restrict__ x, const float* __restrict__ y,
                 float* __restrict__ out)
{
    __shared__ __align__(16) float Wb[5 * WPL];
    __shared__ __align__(16) float Ub[5 * UPL];
    __shared__ float wsum[4];

    const int t  = threadIdx.x;
    const int w0 = blockIdx.x * TW;
    const int h0 = blockIdx.y * TH;
    const int bz = blockIdx.z;
    const int b   = bz >> 2;
    const int zo0 = (bz & 3) * CD;

    const float* xb = x + (size_t)b * (DIM * SLICE);
    const float* yb = y + (size_t)b * (DIM * SLICE);

    // ---- role A (t in [160,256)): row load + products + w-sum ----
    const bool isA = t >= 160;
    const int at = t - 160;
    const int rA = at >> 2;                 // 0..23 halo row
    const int qA = at & 3;                  // 0..3 output w-quad
    const int ghA = min(max(h0 - 4 + rA, 0), DIM - 1);
    const int jlA = w0 - 4 + 4 * qA;        // first loaded element (mod-4 aligned)
    const bool fastA = (jlA >= 0) && (jlA + 11 < DIM);

    // ---- role B (t < 80): h-sum ----
    const int cB = t >> 4;                  // 0..4
    const int rB = t & 15;
    const int wB = (rB >> 2) * 4;           // 0,4,8,12
    const int iB = (rB & 3) * 4;            // 0,4,8,12

    // ---- role C (all 256): one output (h,w) column ----
    const int i4 = t >> 4;
    const int j4 = t & 15;

    float cx[12], cy[12], nx[12], ny[12];
    float hist[9][5];
    float rs[5] = {0.f, 0.f, 0.f, 0.f, 0.f};
    float acc = 0.f;

    auto loadA = [&](int z, float* vx, float* vy) {
        const float* rx = xb + (size_t)z * SLICE + (size_t)ghA * DIM;
        const float* ry = yb + (size_t)z * SLICE + (size_t)ghA * DIM;
        if (fastA) {
            #pragma unroll
            for (int g = 0; g < 3; ++g) {
                const float4 a = *reinterpret_cast<const float4*>(rx + jlA + 4 * g);
                const float4 c = *reinterpret_cast<const float4*>(ry + jlA + 4 * g);
                vx[4*g+0] = a.x; vx[4*g+1] = a.y; vx[4*g+2] = a.z; vx[4*g+3] = a.w;
                vy[4*g+0] = c.x; vy[4*g+1] = c.y; vy[4*g+2] = c.z; vy[4*g+3] = c.w;
            }
        } else {
            #pragma unroll
            for (int m = 0; m < 12; ++m) {
                const int jj = min(max(jlA + m, 0), DIM - 1);
                vx[m] = rx[jj]; vy[m] = ry[jj];
            }
        }
    };

    if (isA) loadA(min(max(zo0 - 4, 0), DIM - 1), cx, cy);

    const int zlast = zo0 + CD + 3;         // 48 input slices: zo0-4 .. zlast
    for (int base = zo0 - 4; base <= zlast; base += 9) {
        #pragma unroll
        for (int p = 0; p < 9; ++p) {       // phase (zi-(zo0-4)) % 9 == p
            const int zi = base + p;
            if (zi <= zlast) {
                // region R: A writes W(zi); prefetch zi+1 issued first so the
                // global latency spans bar1+B+bar2+C before the reg copy.
                if (isA) {
                    if (zi < zlast) loadA(min(max(zi + 1, 0), DIM - 1), nx, ny);
                    #pragma unroll
                    for (int c = 0; c < 5; ++c) {
                        float pr[12];
                        #pragma unroll
                        for (int m = 0; m < 12; ++m)
                            pr[m] = (c == 0) ? cx[m]
                                  : (c == 1) ? cy[m]
                                  : (c == 2) ? cx[m] * cx[m]
                                  : (c == 3) ? cy[m] * cy[m]
                                             : cx[m] * cy[m];
                        float s = pr[0]+pr[1]+pr[2]+pr[3]+pr[4]
                                + pr[5]+pr[6]+pr[7]+pr[8];
                        float4 o;
                        o.x = s;
                        s += pr[9]  - pr[0]; o.y = s;
                        s += pr[10] - pr[1]; o.z = s;
                        s += pr[11] - pr[2]; o.w = s;
                        *reinterpret_cast<float4*>(
                            &Wb[c * WPL + rA * WSTR + 4 * qA]) = o;
                    }
                }
                __syncthreads();            // bar1: W(zi) ready

                if (t < 80) {
                    float4 s = {0,0,0,0};
                    #pragma unroll
                    for (int k = 0; k < 9; ++k)
                        s += *reinterpret_cast<const float4*>(
                                 &Wb[cB*WPL + (iB + k)*WSTR + wB]);
                    *reinterpret_cast<float4*>(&Ub[cB*UPL + iB*USTR + wB]) = s;
                    #pragma unroll
                    for (int m = 1; m < 4; ++m) {
                        s += *reinterpret_cast<const float4*>(
                                 &Wb[cB*WPL + (iB + 8 + m)*WSTR + wB])
                           - *reinterpret_cast<const float4*>(
                                 &Wb[cB*WPL + (iB + m - 1)*WSTR + wB]);
                        *reinterpret_cast<float4*>(
                            &Ub[cB*UPL + (iB + m)*USTR + wB]) = s;
                    }
                }
                __syncthreads();            // bar2: U(zi) ready

                // C: register d-ring + ncc (runs concurrent with next A)
                #pragma unroll
                for (int c = 0; c < 5; ++c) {
                    const float u = Ub[c*UPL + i4*USTR + j4];
                    rs[c] += u;
                    hist[p][c] = u;
                }
                if (zi >= zo0 + 4) {
                    const float inv = 1.0f / 729.0f;
                    const float xm = rs[0]*inv, ym = rs[1]*inv;
                    const float x2 = rs[2]*inv, y2 = rs[3]*inv, xy = rs[4]*inv;
                    const float cross = xy - xm*ym;
                    const float vx_ = x2 - xm*xm;
                    const float vy_ = y2 - ym*ym;
                    acc += cross*cross / (vx_*vy_ + 1e-5f);
                    const int po = (p + 1) % 9;     // slice zi-8 leaves window
                    #pragma unroll
                    for (int c = 0; c < 5; ++c) rs[c] -= hist[po][c];
                }
                if (isA && zi < zlast) {
                    #pragma unroll
                    for (int m = 0; m < 12; ++m) { cx[m] = nx[m]; cy[m] = ny[m]; }
                }
            }
        }
    }

    // ---- block reduction ----
    #pragma unroll
    for (int off = 32; off > 0; off >>= 1)
        acc += __shfl_down(acc, off, 64);
    const int wave = t >> 6;
    if ((t & 63) == 0) wsum[wave] = acc;
    __syncthreads();
    if (t == 0) {
        const float s = wsum[0] + wsum[1] + wsum[2] + wsum[3];
        atomicAdd(out, -s * (1.0f / 8192000.0f));
    }
}

extern "C" void kernel_launch(void* const* d_in, const int* in_sizes, int n_in,
                              void* d_out, int out_size, void* d_ws, size_t ws_size,
                              hipStream_t stream)
{
    const float* x = (const float*)d_in[0];
    const float* y = (const float*)d_in[1];
    float* out = (float*)d_out;

    // d_out is poisoned 0xAA before every call; accumulate atomically on zero
    hipMemsetAsync(out, 0, sizeof(float), stream);

    dim3 grid(DIM / TW, DIM / TH, 2 * (DIM / CD));  // 10 x 10 x 8 = 800 blocks
    lncc_kernel<<<grid, 256, 0, stream>>>(x, y, out);
}

// Round 6
// 194.741 us; speedup vs baseline: 1.0953x; 1.0953x over previous
//
#include <hip/hip_runtime.h>

#define DIM 160
#define SLICE (DIM * DIM)
#define TH 16
#define TW 16
#define CD 20   // output slices per block chunk; 160/CD = 8 chunks per batch

// Fused LNCC, separable order h -> w -> d, each input slice loaded ONCE.
// R3 structure (proven): wide stages, products from a small float4 register
// prefetch, 9-deep per-output d-ring in registers (45 VGPRs, total 60).
// R6 deltas: CD 40->20 (1600 blocks -> 5 resident/CU; LDS 28KB and VGPR 60
// both allow it), stage3 widened to 2 waves via channel split.
#define SIDX(c,i,j) ((c)*680 + (i)*28 + (j))   // S: 24x28 plane (+8 pad)
#define TIDX(c,i,j) ((c)*456 + (i)*28 + (j))   // T: 16x28 plane (+8 pad)
#define UIDX(c,i,j) ((c)*260 + (i)*16 + (j))   // U: 16x16 plane (+4 pad)

__global__ __launch_bounds__(256, 5)
void lncc_kernel(const float* __restrict__ x, const float* __restrict__ y,
                 float* __restrict__ out)
{
    __shared__ __align__(16) float S[5 * 680];
    __shared__ __align__(16) float T[5 * 456];
    __shared__ __align__(16) float U[5 * 260];
    __shared__ float wsum[4];

    const int t  = threadIdx.x;
    const int w0 = blockIdx.x * TW;
    const int h0 = blockIdx.y * TH;
    const int bz = blockIdx.z;
    const int b   = bz >> 3;              // batch
    const int zo0 = (bz & 7) * CD;        // first output slice of chunk

    const float* xb = x + (size_t)b * (DIM * SLICE);
    const float* yb = y + (size_t)b * (DIM * SLICE);

    // ---- stage1 role: halo column group (h1, w41) ----
    const int h1  = t / 6;                // 0..23 valid for t<144
    const int w41 = t - h1 * 6;           // 0..5
    const int gh  = min(max(h0 - 4 + h1, 0), DIM - 1);
    const int gwb = w0 - 4 + 4 * w41;
    const bool fast = (gwb >= 0) && (gwb + 3 < DIM);
    const int jc0 = min(max(gwb + 0, 0), DIM - 1);
    const int jc1 = min(max(gwb + 1, 0), DIM - 1);
    const int jc2 = min(max(gwb + 2, 0), DIM - 1);
    const int jc3 = min(max(gwb + 3, 0), DIM - 1);

    auto load4 = [&](const float* sl) -> float4 {
        const float* row = sl + (size_t)gh * DIM;
        if (fast) return *reinterpret_cast<const float4*>(row + gwb);
        float4 r;
        r.x = row[jc0]; r.y = row[jc1]; r.z = row[jc2]; r.w = row[jc3];
        return r;
    };

    // ---- stage2 role: (channel c2, w-group w42, row-quad i02) ----
    const int c2  = t / 24;               // 0..4 for t<120
    const int r2  = t - c2 * 24;
    const int w42 = r2 >> 2;              // 0..5
    const int i02 = (r2 & 3) * 4;         // 0,4,8,12

    // ---- stage3 role: 2 waves, channel-split (g3=0 -> ch0..2, g3=1 -> ch3..4)
    const int g3 = t >> 6;                // 0 or 1 for t<128
    const int t3 = t & 63;
    const int i3 = t3 >> 2;               // 0..15
    const int j3 = (t3 & 3) * 4;          // 0,4,8,12

    // ---- stage4 role: one output column each ----
    const int i4 = t >> 4;
    const int j4 = t & 15;

    float hist[9][5];                     // register ring (constant indices)
    float rs[5] = {0.f, 0.f, 0.f, 0.f, 0.f};
    float acc = 0.f;

    auto wsum9 = [&](int c) {
        const float4 t0 = *reinterpret_cast<const float4*>(&T[TIDX(c, i3, j3)]);
        const float4 t1 = *reinterpret_cast<const float4*>(&T[TIDX(c, i3, j3 + 4)]);
        const float4 t2 = *reinterpret_cast<const float4*>(&T[TIDX(c, i3, j3 + 8)]);
        float4 uo;
        float s = t0.x + t0.y + t0.z + t0.w
                + t1.x + t1.y + t1.z + t1.w + t2.x;
        uo.x = s;
        s += t2.y - t0.x; uo.y = s;
        s += t2.z - t0.y; uo.z = s;
        s += t2.w - t0.z; uo.w = s;
        *reinterpret_cast<float4*>(&U[UIDX(c, i3, j3)]) = uo;
    };

    // prefetch first slice
    float4 xv = {0,0,0,0}, yv = {0,0,0,0};
    {
        const int z0 = min(max(zo0 - 4, 0), DIM - 1);
        if (t < 144) {
            xv = load4(xb + (size_t)z0 * SLICE);
            yv = load4(yb + (size_t)z0 * SLICE);
        }
    }

    const int zlast = zo0 + CD + 3;       // CD+8 input slices: zo0-4 .. zlast
    for (int base = zo0 - 4; base <= zlast; base += 9) {
        #pragma unroll
        for (int p = 0; p < 9; ++p) {
            const int zi = base + p;      // phase (zi - (zo0-4)) % 9 == p
            if (zi <= zlast) {
                // stage1: products of prefetched slice -> S
                if (t < 144) {
                    const int jw = 4 * w41;
                    *reinterpret_cast<float4*>(&S[SIDX(0, h1, jw)]) = xv;
                    *reinterpret_cast<float4*>(&S[SIDX(1, h1, jw)]) = yv;
                    *reinterpret_cast<float4*>(&S[SIDX(2, h1, jw)]) = xv * xv;
                    *reinterpret_cast<float4*>(&S[SIDX(3, h1, jw)]) = yv * yv;
                    *reinterpret_cast<float4*>(&S[SIDX(4, h1, jw)]) = xv * yv;
                }
                __syncthreads();

                // prefetch next slice (consumed next iteration, after 2 bars)
                if (t < 144 && zi < zlast) {
                    const int zn = min(max(zi + 1, 0), DIM - 1);
                    xv = load4(xb + (size_t)zn * SLICE);
                    yv = load4(yb + (size_t)zn * SLICE);
                }

                // stage2: 9-tap h-sum S->T (b128 slide over 4 rows)
                if (t < 120) {
                    const int jw = 4 * w42;
                    float4 s = {0,0,0,0};
                    #pragma unroll
                    for (int k = 0; k < 9; ++k)
                        s += *reinterpret_cast<const float4*>(&S[SIDX(c2, i02 + k, jw)]);
                    *reinterpret_cast<float4*>(&T[TIDX(c2, i02, jw)]) = s;
                    #pragma unroll
                    for (int m = 1; m < 4; ++m) {
                        s += *reinterpret_cast<const float4*>(&S[SIDX(c2, i02 + 8 + m, jw)])
                           - *reinterpret_cast<const float4*>(&S[SIDX(c2, i02 + m - 1, jw)]);
                        *reinterpret_cast<float4*>(&T[TIDX(c2, i02 + m, jw)]) = s;
                    }
                }
                __syncthreads();

                // stage3: 9-tap w-sum T->U (b128 slide, 2 waves, ch-split)
                if (t < 128) {
                    if (g3 == 0) { wsum9(0); wsum9(1); wsum9(2); }
                    else         { wsum9(3); wsum9(4); }
                }
                __syncthreads();

                // stage4: register d-ring update + ncc emit
                #pragma unroll
                for (int c = 0; c < 5; ++c) {
                    const float u = U[UIDX(c, i4, j4)];
                    rs[c] += u;
                    hist[p][c] = u;
                }
                if (zi >= zo0 + 4) {
                    const float inv = 1.0f / 729.0f;
                    const float xm = rs[0] * inv, ym = rs[1] * inv;
                    const float x2 = rs[2] * inv, y2 = rs[3] * inv;
                    const float xy = rs[4] * inv;
                    const float cross = xy - xm * ym;
                    const float vx = x2 - xm * xm;
                    const float vy = y2 - ym * ym;
                    acc += cross * cross / (vx * vy + 1e-5f);
                    const int po = (p + 1) % 9;    // slice zi-8 leaves window
                    #pragma unroll
                    for (int c = 0; c < 5; ++c)
                        rs[c] -= hist[po][c];
                }
                // stage4 U-reads are ordered before next slice's U-writes by
                // the next iteration's bar1+bar2
            }
        }
    }

    // ---- block reduction: wave shuffle, then 4 partials via LDS ----
    #pragma unroll
    for (int off = 32; off > 0; off >>= 1)
        acc += __shfl_down(acc, off, 64);
    const int wave = t >> 6;
    if ((t & 63) == 0) wsum[wave] = acc;
    __syncthreads();
    if (t == 0) {
        const float s = wsum[0] + wsum[1] + wsum[2] + wsum[3];
        atomicAdd(out, -s * (1.0f / 8192000.0f));
    }
}

extern "C" void kernel_launch(void* const* d_in, const int* in_sizes, int n_in,
                              void* d_out, int out_size, void* d_ws, size_t ws_size,
                              hipStream_t stream)
{
    const float* x = (const float*)d_in[0];
    const float* y = (const float*)d_in[1];
    float* out = (float*)d_out;

    // d_out is poisoned 0xAA before every call; accumulate atomically on zero
    hipMemsetAsync(out, 0, sizeof(float), stream);

    dim3 grid(DIM / TW, DIM / TH, 2 * (DIM / CD));  // 10 x 10 x 16 = 1600 blocks
    lncc_kernel<<<grid, 256, 0, stream>>>(x, y, out);
}

// Round 7
// 165.148 us; speedup vs baseline: 1.2916x; 1.1792x over previous
//
#include <hip/hip_runtime.h>

#define DIM 160
#define SLICE (DIM * DIM)
#define TH 16
#define TW 16
#define CD 20   // output slices per block chunk; 160/CD = 8 chunks per batch

// Fused LNCC, separable order h -> w -> d, each input slice loaded ONCE.
// R3 structure (proven): wide stages, products from a small float4 register
// prefetch, 9-deep per-output d-ring in registers/AGPRs.
// R7 delta vs R6: __launch_bounds__ back to (256,4) — (256,5) squeezed the
// unified VGPR+AGPR budget to ~102/lane, spilling hist[9][5] to scratch
// (WRITE_SIZE 25KB -> 115MB). At 4 waves/EU the ring fits in AGPRs.
#define SIDX(c,i,j) ((c)*680 + (i)*28 + (j))   // S: 24x28 plane (+8 pad)
#define TIDX(c,i,j) ((c)*456 + (i)*28 + (j))   // T: 16x28 plane (+8 pad)
#define UIDX(c,i,j) ((c)*260 + (i)*16 + (j))   // U: 16x16 plane (+4 pad)

__global__ __launch_bounds__(256, 4)
void lncc_kernel(const float* __restrict__ x, const float* __restrict__ y,
                 float* __restrict__ out)
{
    __shared__ __align__(16) float S[5 * 680];
    __shared__ __align__(16) float T[5 * 456];
    __shared__ __align__(16) float U[5 * 260];
    __shared__ float wsum[4];

    const int t  = threadIdx.x;
    const int w0 = blockIdx.x * TW;
    const int h0 = blockIdx.y * TH;
    const int bz = blockIdx.z;
    const int b   = bz >> 3;              // batch
    const int zo0 = (bz & 7) * CD;        // first output slice of chunk

    const float* xb = x + (size_t)b * (DIM * SLICE);
    const float* yb = y + (size_t)b * (DIM * SLICE);

    // ---- stage1 role: halo column group (h1, w41) ----
    const int h1  = t / 6;                // 0..23 valid for t<144
    const int w41 = t - h1 * 6;           // 0..5
    const int gh  = min(max(h0 - 4 + h1, 0), DIM - 1);
    const int gwb = w0 - 4 + 4 * w41;
    const bool fast = (gwb >= 0) && (gwb + 3 < DIM);
    const int jc0 = min(max(gwb + 0, 0), DIM - 1);
    const int jc1 = min(max(gwb + 1, 0), DIM - 1);
    const int jc2 = min(max(gwb + 2, 0), DIM - 1);
    const int jc3 = min(max(gwb + 3, 0), DIM - 1);

    auto load4 = [&](const float* sl) -> float4 {
        const float* row = sl + (size_t)gh * DIM;
        if (fast) return *reinterpret_cast<const float4*>(row + gwb);
        float4 r;
        r.x = row[jc0]; r.y = row[jc1]; r.z = row[jc2]; r.w = row[jc3];
        return r;
    };

    // ---- stage2 role: (channel c2, w-group w42, row-quad i02) ----
    const int c2  = t / 24;               // 0..4 for t<120
    const int r2  = t - c2 * 24;
    const int w42 = r2 >> 2;              // 0..5
    const int i02 = (r2 & 3) * 4;         // 0,4,8,12

    // ---- stage3 role: 2 waves, channel-split (g3=0 -> ch0..2, g3=1 -> ch3..4)
    const int g3 = t >> 6;                // 0 or 1 for t<128
    const int t3 = t & 63;
    const int i3 = t3 >> 2;               // 0..15
    const int j3 = (t3 & 3) * 4;          // 0,4,8,12

    // ---- stage4 role: one output column each ----
    const int i4 = t >> 4;
    const int j4 = t & 15;

    float hist[9][5];                     // register ring (constant indices)
    float rs[5] = {0.f, 0.f, 0.f, 0.f, 0.f};
    float acc = 0.f;

    auto wsum9 = [&](int c) {
        const float4 t0 = *reinterpret_cast<const float4*>(&T[TIDX(c, i3, j3)]);
        const float4 t1 = *reinterpret_cast<const float4*>(&T[TIDX(c, i3, j3 + 4)]);
        const float4 t2 = *reinterpret_cast<const float4*>(&T[TIDX(c, i3, j3 + 8)]);
        float4 uo;
        float s = t0.x + t0.y + t0.z + t0.w
                + t1.x + t1.y + t1.z + t1.w + t2.x;
        uo.x = s;
        s += t2.y - t0.x; uo.y = s;
        s += t2.z - t0.y; uo.z = s;
        s += t2.w - t0.z; uo.w = s;
        *reinterpret_cast<float4*>(&U[UIDX(c, i3, j3)]) = uo;
    };

    // prefetch first slice
    float4 xv = {0,0,0,0}, yv = {0,0,0,0};
    {
        const int z0 = min(max(zo0 - 4, 0), DIM - 1);
        if (t < 144) {
            xv = load4(xb + (size_t)z0 * SLICE);
            yv = load4(yb + (size_t)z0 * SLICE);
        }
    }

    const int zlast = zo0 + CD + 3;       // CD+8 input slices: zo0-4 .. zlast
    for (int base = zo0 - 4; base <= zlast; base += 9) {
        #pragma unroll
        for (int p = 0; p < 9; ++p) {
            const int zi = base + p;      // phase (zi - (zo0-4)) % 9 == p
            if (zi <= zlast) {
                // stage1: products of prefetched slice -> S
                if (t < 144) {
                    const int jw = 4 * w41;
                    *reinterpret_cast<float4*>(&S[SIDX(0, h1, jw)]) = xv;
                    *reinterpret_cast<float4*>(&S[SIDX(1, h1, jw)]) = yv;
                    *reinterpret_cast<float4*>(&S[SIDX(2, h1, jw)]) = xv * xv;
                    *reinterpret_cast<float4*>(&S[SIDX(3, h1, jw)]) = yv * yv;
                    *reinterpret_cast<float4*>(&S[SIDX(4, h1, jw)]) = xv * yv;
                }
                __syncthreads();

                // prefetch next slice (consumed next iteration, after 2 bars)
                if (t < 144 && zi < zlast) {
                    const int zn = min(max(zi + 1, 0), DIM - 1);
                    xv = load4(xb + (size_t)zn * SLICE);
                    yv = load4(yb + (size_t)zn * SLICE);
                }

                // stage2: 9-tap h-sum S->T (b128 slide over 4 rows)
                if (t < 120) {
                    const int jw = 4 * w42;
                    float4 s = {0,0,0,0};
                    #pragma unroll
                    for (int k = 0; k < 9; ++k)
                        s += *reinterpret_cast<const float4*>(&S[SIDX(c2, i02 + k, jw)]);
                    *reinterpret_cast<float4*>(&T[TIDX(c2, i02, jw)]) = s;
                    #pragma unroll
                    for (int m = 1; m < 4; ++m) {
                        s += *reinterpret_cast<const float4*>(&S[SIDX(c2, i02 + 8 + m, jw)])
                           - *reinterpret_cast<const float4*>(&S[SIDX(c2, i02 + m - 1, jw)]);
                        *reinterpret_cast<float4*>(&T[TIDX(c2, i02 + m, jw)]) = s;
                    }
                }
                __syncthreads();

                // stage3: 9-tap w-sum T->U (b128 slide, 2 waves, ch-split)
                if (t < 128) {
                    if (g3 == 0) { wsum9(0); wsum9(1); wsum9(2); }
                    else         { wsum9(3); wsum9(4); }
                }
                __syncthreads();

                // stage4: register d-ring update + ncc emit
                #pragma unroll
                for (int c = 0; c < 5; ++c) {
                    const float u = U[UIDX(c, i4, j4)];
                    rs[c] += u;
                    hist[p][c] = u;
                }
                if (zi >= zo0 + 4) {
                    const float inv = 1.0f / 729.0f;
                    const float xm = rs[0] * inv, ym = rs[1] * inv;
                    const float x2 = rs[2] * inv, y2 = rs[3] * inv;
                    const float xy = rs[4] * inv;
                    const float cross = xy - xm * ym;
                    const float vx = x2 - xm * xm;
                    const float vy = y2 - ym * ym;
                    acc += cross * cross / (vx * vy + 1e-5f);
                    const int po = (p + 1) % 9;    // slice zi-8 leaves window
                    #pragma unroll
                    for (int c = 0; c < 5; ++c)
                        rs[c] -= hist[po][c];
                }
                // stage4 U-reads are ordered before next slice's U-writes by
                // the next iteration's bar1+bar2
            }
        }
    }

    // ---- block reduction: wave shuffle, then 4 partials via LDS ----
    #pragma unroll
    for (int off = 32; off > 0; off >>= 1)
        acc += __shfl_down(acc, off, 64);
    const int wave = t >> 6;
    if ((t & 63) == 0) wsum[wave] = acc;
    __syncthreads();
    if (t == 0) {
        const float s = wsum[0] + wsum[1] + wsum[2] + wsum[3];
        atomicAdd(out, -s * (1.0f / 8192000.0f));
    }
}

extern "C" void kernel_launch(void* const* d_in, const int* in_sizes, int n_in,
                              void* d_out, int out_size, void* d_ws, size_t ws_size,
                              hipStream_t stream)
{
    const float* x = (const float*)d_in[0];
    const float* y = (const float*)d_in[1];
    float* out = (float*)d_out;

    // d_out is poisoned 0xAA before every call; accumulate atomically on zero
    hipMemsetAsync(out, 0, sizeof(float), stream);

    dim3 grid(DIM / TW, DIM / TH, 2 * (DIM / CD));  // 10 x 10 x 16 = 1600 blocks
    lncc_kernel<<<grid, 256, 0, stream>>>(x, y, out);
}